// Round 5
// baseline (671.704 us; speedup 1.0000x reference)
//
#include <hip/hip_runtime.h>
#include <hip/hip_bf16.h>

#define N_NODES 20000
#define N_EDGES 320000
#define TOT_E   (N_EDGES + N_NODES)   // 340000 with self loops
#define IN_CH   128
#define HEADS   8
#define CH      33
#define DD      264                   // HEADS*CH
#define OUTW    132
#define NEG     0.2f

#define LDH     272                   // hB row stride (17 * 16)
#define LDB     272                   // bf16 payload row stride
#define LDA     288                   // hA (hi/lo bf16) row stride, K padded to 9*32
#define NT_HID  17                    // N tiles (16 wide) for hidden gemms
#define NT_HEAD 9                     // N tiles for head gemm (132 -> 144)

typedef unsigned short ushort;
typedef short bf16x8 __attribute__((ext_vector_type(8)));
typedef float f32x4  __attribute__((ext_vector_type(4)));

__device__ inline void split2(float v, ushort& hi, ushort& lo) {
    __hip_bfloat16 h = __float2bfloat16(v);
    float r = v - __bfloat162float(h);
    __hip_bfloat16 l = __float2bfloat16(r);
    hi = *(ushort*)&h;
    lo = *(ushort*)&l;
}

__device__ inline float bf2f(ushort u) {
    union { unsigned int i; float f; } c;
    c.i = ((unsigned int)u) << 16;
    return c.f;
}

// ---------------- CSR build ----------------

__global__ void deg_k(const int* __restrict__ ei, int* __restrict__ deg) {
    int e = blockIdx.x * 256 + threadIdx.x;
    if (e >= TOT_E) return;
    int dst = (e < N_EDGES) ? ei[N_EDGES + e] : (e - N_EDGES);
    atomicAdd(&deg[dst], 1);
}

__global__ __launch_bounds__(1024) void scan_k(const int* __restrict__ deg,
                                               int* __restrict__ rowp) {
    __shared__ int part[1024];
    const int PER = 20;
    int t = threadIdx.x;
    int base = t * PER;
    int s = 0;
    for (int i = 0; i < PER; ++i) {
        int idx = base + i;
        if (idx < N_NODES) s += deg[idx];
    }
    part[t] = s;
    __syncthreads();
    for (int off = 1; off < 1024; off <<= 1) {
        int v = 0;
        if (t >= off) v = part[t - off];
        __syncthreads();
        part[t] += v;
        __syncthreads();
    }
    int run = part[t] - s;
    for (int i = 0; i < PER; ++i) {
        int idx = base + i;
        if (idx < N_NODES) { rowp[idx] = run; run += deg[idx]; }
    }
    if (t == 1023) rowp[N_NODES] = part[1023];
}

__global__ void fill_k(const int* __restrict__ ei, const int* __restrict__ rowp,
                       int* __restrict__ cur, int* __restrict__ csr) {
    int e = blockIdx.x * 256 + threadIdx.x;
    if (e >= TOT_E) return;
    int src, dst;
    if (e < N_EDGES) { src = ei[e]; dst = ei[N_EDGES + e]; }
    else             { src = dst = e - N_EDGES; }
    int p = atomicAdd(&cur[dst], 1);
    csr[rowp[dst] + p] = src;
}

// ---------------- input x -> hi/lo bf16 split (into hA, stride LDA) ----------------

__global__ void splitx_k(const float* __restrict__ x,
                         ushort* __restrict__ ahi, ushort* __restrict__ alo) {
    int idx = blockIdx.x * 256 + threadIdx.x;
    if (idx >= N_NODES * IN_CH) return;
    int n = idx >> 7, k = idx & 127;
    ushort hi, lo;
    split2(x[idx], hi, lo);
    ahi[(size_t)n * LDA + k] = hi;
    alo[(size_t)n * LDA + k] = lo;
}

// ---------------- weight -> fragment-ordered hi/lo bf16 ----------------

__global__ void convw_k(const float* __restrict__ W, int K, int NC, int NT,
                        ushort* __restrict__ fhi, ushort* __restrict__ flo,
                        int total) {
    int gid = blockIdx.x * 256 + threadIdx.x;
    if (gid >= total) return;   // total = panels*NT*64
    int p = gid / (NT * 64);
    int rem = gid % (NT * 64);
    int t = rem >> 6, c = rem & 63;
    int kq = c >> 4, m = c & 15;
    int n = t * 16 + m;
    ushort hi8[8], lo8[8];
#pragma unroll
    for (int j = 0; j < 8; ++j) {
        int k = p * 32 + kq * 8 + j;
        float v = (k < K && n < NC) ? W[(size_t)k * NC + n] : 0.f;
        split2(v, hi8[j], lo8[j]);
    }
    size_t o = ((size_t)gid) * 8;
#pragma unroll
    for (int j = 0; j < 8; ++j) { fhi[o + j] = hi8[j]; flo[o + j] = lo8[j]; }
}

// ---------------- MFMA GEMM: C[M, NC] = A[M, K] @ B[K, NC] ----------------

__global__ __launch_bounds__(256) void gemm_mfma(
    const ushort* __restrict__ Ahi, const ushort* __restrict__ Alo, int lda, int kpanels,
    const ushort* __restrict__ Bhi, const ushort* __restrict__ Blo, int NTtot,
    float* __restrict__ C, int ldc, int ncguard, const float* __restrict__ bias,
    ushort* __restrict__ Cb16) {
    __shared__ ushort Al[2][4][512];   // [hi/lo][wave m-tile][chunk*8]
    __shared__ ushort Bl[2][9][512];   // [hi/lo][n-tile][chunk*8]
    int tid = threadIdx.x;
    int m0 = blockIdx.x * 64;
    int t0 = blockIdx.y * 9;
    int nt = NTtot - t0; if (nt > 9) nt = 9;

    f32x4 acc[9];
#pragma unroll
    for (int t = 0; t < 9; ++t) acc[t] = (f32x4){0.f, 0.f, 0.f, 0.f};

    int w = tid >> 6, lane = tid & 63;

    for (int p = 0; p < kpanels; ++p) {
#pragma unroll
        for (int i = 0; i < 2; ++i) {
            int id = tid + 256 * i;
            int hl = id >> 8;          // 0 = hi, 1 = lo
            int cid = id & 255;
            int mrow = cid >> 2, kq = cid & 3;
            int gm = m0 + mrow;
            uint4 v = {0, 0, 0, 0};
            if (gm < N_NODES) {
                const ushort* src = (hl ? Alo : Ahi) + (size_t)gm * lda + p * 32 + kq * 8;
                v = *(const uint4*)src;
            }
            *(uint4*)&Al[hl][mrow >> 4][(kq * 16 + (mrow & 15)) * 8] = v;
        }
        int nb = nt * 64;
        for (int id = tid; id < 2 * nb; id += 256) {
            int hl = id >= nb;
            int c2 = id - hl * nb;
            int t = c2 >> 6, c = c2 & 63;
            const ushort* src = (hl ? Blo : Bhi) + ((size_t)(p * NTtot + t0 + t) * 64 + c) * 8;
            *(uint4*)&Bl[hl][t][c * 8] = *(const uint4*)src;
        }
        __syncthreads();

        bf16x8 ahi = *(const bf16x8*)&Al[0][w][lane * 8];
        bf16x8 alo = *(const bf16x8*)&Al[1][w][lane * 8];
#pragma unroll
        for (int t = 0; t < 9; ++t) {
            if (t < nt) {
                bf16x8 bh = *(const bf16x8*)&Bl[0][t][lane * 8];
                bf16x8 bl = *(const bf16x8*)&Bl[1][t][lane * 8];
                acc[t] = __builtin_amdgcn_mfma_f32_16x16x32_bf16(ahi, bh, acc[t], 0, 0, 0);
                acc[t] = __builtin_amdgcn_mfma_f32_16x16x32_bf16(ahi, bl, acc[t], 0, 0, 0);
                acc[t] = __builtin_amdgcn_mfma_f32_16x16x32_bf16(alo, bh, acc[t], 0, 0, 0);
            }
        }
        __syncthreads();
    }

    // store: C/D layout col = lane&15, row = (lane>>4)*4 + r
    int rbase = m0 + w * 16 + ((lane >> 4) << 2);
    int cbase = t0 * 16 + (lane & 15);
#pragma unroll
    for (int t = 0; t < 9; ++t) {
        if (t < nt) {
            int gn = cbase + t * 16;
            if (gn >= ncguard) continue;
            float b = bias ? bias[gn] : 0.f;
#pragma unroll
            for (int r = 0; r < 4; ++r) {
                int gm = rbase + r;
                if (gm < N_NODES) {
                    float v = acc[t][r] + b;
                    C[(size_t)gm * ldc + gn] = v;
                    if (Cb16) {
                        __hip_bfloat16 bv = __float2bfloat16(v);
                        Cb16[(size_t)gm * LDB + gn] = *(ushort*)&bv;
                    }
                }
            }
        }
    }
}

// ---------------- attention logits per (node, head) ----------------

__global__ void alpha_k(const float* __restrict__ xh,
                        const float* __restrict__ a_s, const float* __restrict__ a_d,
                        float* __restrict__ as_, float* __restrict__ ad_) {
    int t = blockIdx.x * 256 + threadIdx.x;
    if (t >= N_NODES * HEADS) return;
    int n = t >> 3, h = t & 7;
    const float* row = xh + (size_t)n * LDH + h * CH;
    float ss = 0.f, sd = 0.f;
#pragma unroll
    for (int i = 0; i < CH; ++i) {
        float v = row[i];
        ss += v * a_s[h * CH + i];
        sd += v * a_d[h * CH + i];
    }
    as_[t] = ss;
    ad_[t] = sd;
}

// ---------------- per-(node,head) softmax stats + unnormalized edge weights ----------------
// thread t = node*8 + h. Same-node heads are consecutive tids -> coalesced as_ gathers.

__global__ __launch_bounds__(256) void stat2_k(
    const float* __restrict__ as_, const float* __restrict__ ad_,
    const int* __restrict__ rowp, const int* __restrict__ csr,
    float* __restrict__ alpha, float* __restrict__ inv_) {
    int t = blockIdx.x * 256 + threadIdx.x;
    if (t >= N_NODES * HEADS) return;
    int node = t >> 3, h = t & 7;
    int r0 = rowp[node], dg = rowp[node + 1] - r0;
    float adh = ad_[t];

    float m = -1e30f;
    for (int j = 0; j < dg; ++j) {
        int s = csr[r0 + j];
        float e = as_[s * 8 + h] + adh;
        e = e > 0.f ? e : NEG * e;
        m = fmaxf(m, e);
    }
    float sum = 0.f;
    for (int j = 0; j < dg; ++j) {
        int s = csr[r0 + j];
        float e = as_[s * 8 + h] + adh;
        e = e > 0.f ? e : NEG * e;
        float ex = __expf(e - m);
        sum += ex;
        alpha[(size_t)(r0 + j) * 8 + h] = ex;
    }
    inv_[t] = 1.0f / (sum + 1e-16f);
}

// ---------------- gather-aggregate: 4 nodes per block (1 wave each), no LDS, no barriers ----

__global__ __launch_bounds__(256) void gat_k(
    const ushort* __restrict__ xb, const float* __restrict__ alpha,
    const float* __restrict__ inv_, const int* __restrict__ rowp,
    const int* __restrict__ csr, const float* __restrict__ bias,
    ushort* __restrict__ outhi, ushort* __restrict__ outlo) {
    int node = blockIdx.x * 4 + (threadIdx.x >> 6);
    if (node >= N_NODES) return;
    int lane = threadIdx.x & 63;
    int r0 = rowp[node], dg = rowp[node + 1] - r0;

    int h0[4], h1[4];
#pragma unroll
    for (int j = 0; j < 4; ++j) {
        h0[j] = (4 * lane + j) / 33;
        h1[j] = (4 * (lane + 64) + j) / 33;   // lanes 0,1 only (channels 256..263, head 7)
    }

    float4 a0a = {0.f,0.f,0.f,0.f}, a0b = {0.f,0.f,0.f,0.f};
    float4 a1a = {0.f,0.f,0.f,0.f}, a1b = {0.f,0.f,0.f,0.f};

    int jj = 0;
    for (; jj + 2 <= dg; jj += 2) {
        int s0 = csr[r0 + jj], s1 = csr[r0 + jj + 1];
        const float* ap0 = alpha + (size_t)(r0 + jj) * 8;
        const float* ap1 = ap0 + 8;
        const ushort4* row0 = (const ushort4*)(xb + (size_t)s0 * LDB);
        const ushort4* row1 = (const ushort4*)(xb + (size_t)s1 * LDB);
        ushort4 v0 = row0[lane];
        ushort4 v1 = row1[lane];
        a0a.x += ap0[h0[0]] * bf2f(v0.x);
        a0a.y += ap0[h0[1]] * bf2f(v0.y);
        a0a.z += ap0[h0[2]] * bf2f(v0.z);
        a0a.w += ap0[h0[3]] * bf2f(v0.w);
        a0b.x += ap1[h0[0]] * bf2f(v1.x);
        a0b.y += ap1[h0[1]] * bf2f(v1.y);
        a0b.z += ap1[h0[2]] * bf2f(v1.z);
        a0b.w += ap1[h0[3]] * bf2f(v1.w);
        if (lane < 2) {
            ushort4 w0 = row0[64 + lane];
            ushort4 w1 = row1[64 + lane];
            a1a.x += ap0[h1[0]] * bf2f(w0.x);
            a1a.y += ap0[h1[1]] * bf2f(w0.y);
            a1a.z += ap0[h1[2]] * bf2f(w0.z);
            a1a.w += ap0[h1[3]] * bf2f(w0.w);
            a1b.x += ap1[h1[0]] * bf2f(w1.x);
            a1b.y += ap1[h1[1]] * bf2f(w1.y);
            a1b.z += ap1[h1[2]] * bf2f(w1.z);
            a1b.w += ap1[h1[3]] * bf2f(w1.w);
        }
    }
    if (jj < dg) {
        int s0 = csr[r0 + jj];
        const float* ap0 = alpha + (size_t)(r0 + jj) * 8;
        const ushort4* row0 = (const ushort4*)(xb + (size_t)s0 * LDB);
        ushort4 v0 = row0[lane];
        a0a.x += ap0[h0[0]] * bf2f(v0.x);
        a0a.y += ap0[h0[1]] * bf2f(v0.y);
        a0a.z += ap0[h0[2]] * bf2f(v0.z);
        a0a.w += ap0[h0[3]] * bf2f(v0.w);
        if (lane < 2) {
            ushort4 w0 = row0[64 + lane];
            a1a.x += ap0[h1[0]] * bf2f(w0.x);
            a1a.y += ap0[h1[1]] * bf2f(w0.y);
            a1a.z += ap0[h1[2]] * bf2f(w0.z);
            a1a.w += ap0[h1[3]] * bf2f(w0.w);
        }
    }

    // normalize by per-(node,head) inverse denom
    const float* ivp = inv_ + node * 8;
    float4 acc0, acc1;
    acc0.x = (a0a.x + a0b.x) * ivp[h0[0]];
    acc0.y = (a0a.y + a0b.y) * ivp[h0[1]];
    acc0.z = (a0a.z + a0b.z) * ivp[h0[2]];
    acc0.w = (a0a.w + a0b.w) * ivp[h0[3]];
    acc1.x = (a1a.x + a1b.x) * ivp[h1[0]];
    acc1.y = (a1a.y + a1b.y) * ivp[h1[1]];
    acc1.z = (a1a.z + a1b.z) * ivp[h1[2]];
    acc1.w = (a1a.w + a1b.w) * ivp[h1[3]];

    // epilogue: bias + elu, split to hi/lo bf16 (next gemm A operand), zero K-pad
#pragma unroll
    for (int k = 0; k < 2; ++k) {
        int i4 = lane + 64 * k;
        if (i4 < 66) {
            float4 a = (k == 0) ? acc0 : acc1;
            float vals[4] = {a.x, a.y, a.z, a.w};
            ushort hi4[4], lo4[4];
#pragma unroll
            for (int j = 0; j < 4; ++j) {
                float v = vals[j] + bias[i4 * 4 + j];
                v = v > 0.f ? v : (__expf(v) - 1.f);
                split2(v, hi4[j], lo4[j]);
            }
            size_t o = (size_t)node * LDA + i4 * 4;
            *(ushort4*)(outhi + o) = *(ushort4*)hi4;
            *(ushort4*)(outlo + o) = *(ushort4*)lo4;
        } else if (i4 < 72) {
            ushort4 z = {0, 0, 0, 0};
            size_t o = (size_t)node * LDA + i4 * 4;
            *(ushort4*)(outhi + o) = z;
            *(ushort4*)(outlo + o) = z;
        }
    }
}

// ---------------- launch ----------------

extern "C" void kernel_launch(void* const* d_in, const int* in_sizes, int n_in,
                              void* d_out, int out_size, void* d_ws, size_t ws_size,
                              hipStream_t stream) {
    const float* x  = (const float*)d_in[0];
    const int*   ei = (const int*)d_in[1];
    const float* W[4]  = {(const float*)d_in[2],  (const float*)d_in[6],
                          (const float*)d_in[10], (const float*)d_in[14]};
    const float* As[4] = {(const float*)d_in[3],  (const float*)d_in[7],
                          (const float*)d_in[11], (const float*)d_in[15]};
    const float* Ad[4] = {(const float*)d_in[4],  (const float*)d_in[8],
                          (const float*)d_in[12], (const float*)d_in[16]};
    const float* Bb[4] = {(const float*)d_in[5],  (const float*)d_in[9],
                          (const float*)d_in[13], (const float*)d_in[17]};
    const float* Wh = (const float*)d_in[18];
    const float* bh = (const float*)d_in[19];

    // ---- workspace carve ----
    char* p = (char*)d_ws;
    float* hB    = (float*)p;           p += (size_t)N_NODES * LDH * 4;      // xh fp32
    ushort* hBb  = (ushort*)p;          p += (size_t)N_NODES * LDB * 2;      // xh bf16 payload
    ushort* hAhi = (ushort*)p;          p += (size_t)N_NODES * LDA * 2;      // A hi
    ushort* hAlo = (ushort*)p;          p += (size_t)N_NODES * LDA * 2;      // A lo
    float* as_  = (float*)p;            p += (size_t)N_NODES * HEADS * 4;
    float* ad_  = (float*)p;            p += (size_t)N_NODES * HEADS * 4;
    float* inv_ = (float*)p;            p += (size_t)N_NODES * HEADS * 4;
    float* alpha = (float*)p;           p += (size_t)TOT_E * HEADS * 4;      // unnormalized edge wts
    const int wsz0 = 4 * NT_HID * 512;
    const int wszH = 9 * NT_HID * 512;
    const int wszO = 9 * NT_HEAD * 512;
    ushort* wfhi[4]; ushort* wflo[4];
    for (int l = 0; l < 4; ++l) {
        int sz = (l == 0) ? wsz0 : wszH;
        wfhi[l] = (ushort*)p; p += (size_t)sz * 2;
        wflo[l] = (ushort*)p; p += (size_t)sz * 2;
    }
    ushort* whhi = (ushort*)p; p += (size_t)wszO * 2;
    ushort* whlo = (ushort*)p; p += (size_t)wszO * 2;
    int* deg  = (int*)p;  p += N_NODES * 4;
    int* cur  = (int*)p;  p += N_NODES * 4;
    int* rowp = (int*)p;  p += (N_NODES + 1) * 4;
    int* csr  = (int*)p;  p += (size_t)TOT_E * 4;

    // ---- CSR build ----
    hipMemsetAsync(deg, 0, sizeof(int) * 2 * N_NODES, stream);  // deg + cur
    int egrid = (TOT_E + 255) / 256;
    deg_k<<<egrid, 256, 0, stream>>>(ei, deg);
    scan_k<<<1, 1024, 0, stream>>>(deg, rowp);
    fill_k<<<egrid, 256, 0, stream>>>(ei, rowp, cur, csr);

    // ---- weight + input conversion ----
    splitx_k<<<(N_NODES * IN_CH + 255) / 256, 256, 0, stream>>>(x, hAhi, hAlo);
    {
        int tot = 4 * NT_HID * 64;
        convw_k<<<(tot + 255) / 256, 256, 0, stream>>>(W[0], IN_CH, DD, NT_HID, wfhi[0], wflo[0], tot);
    }
    for (int l = 1; l < 4; ++l) {
        int tot = 9 * NT_HID * 64;
        convw_k<<<(tot + 255) / 256, 256, 0, stream>>>(W[l], DD, DD, NT_HID, wfhi[l], wflo[l], tot);
    }
    {
        int tot = 9 * NT_HEAD * 64;
        convw_k<<<(tot + 255) / 256, 256, 0, stream>>>(Wh, DD, OUTW, NT_HEAD, whhi, whlo, tot);
    }

    dim3 gG((N_NODES + 63) / 64, 2);   // hidden gemms: 17 tiles = 9 + 8
    dim3 gO((N_NODES + 63) / 64, 1);   // head gemm: 9 tiles
    int agrid = (N_NODES * HEADS + 255) / 256;
    int ggrid = (N_NODES + 3) / 4;

    for (int l = 0; l < 4; ++l) {
        int kp = (l == 0) ? 4 : 9;
        gemm_mfma<<<gG, 256, 0, stream>>>(hAhi, hAlo, LDA, kp,
                                          wfhi[l], wflo[l], NT_HID,
                                          hB, LDH, LDH, nullptr, hBb);
        alpha_k<<<agrid, 256, 0, stream>>>(hB, As[l], Ad[l], as_, ad_);
        stat2_k<<<agrid, 256, 0, stream>>>(as_, ad_, rowp, csr, alpha, inv_);
        gat_k<<<ggrid, 256, 0, stream>>>(hBb, alpha, inv_, rowp, csr, Bb[l], hAhi, hAlo);
    }

    // head readout -> fp32 out [N, 132]
    gemm_mfma<<<gO, 256, 0, stream>>>(hAhi, hAlo, LDA, 9,
                                      whhi, whlo, NT_HEAD,
                                      (float*)d_out, OUTW, OUTW, bh, nullptr);
}

// Round 6
// 622.874 us; speedup vs baseline: 1.0784x; 1.0784x over previous
//
#include <hip/hip_runtime.h>
#include <hip/hip_bf16.h>

#define N_NODES 20000
#define N_EDGES 320000
#define TOT_E   (N_EDGES + N_NODES)   // 340000 with self loops
#define IN_CH   128
#define HEADS   8
#define CH      33
#define DD      264                   // HEADS*CH
#define OUTW    132
#define NEG     0.2f

#define LDH     272                   // hB row stride (17 * 16)
#define LDB     272                   // bf16 payload row stride
#define LDA     288                   // hA bf16 row stride, K padded to 9*32
#define NT_HID  17                    // N tiles (16 wide) for hidden gemms
#define NT_HEAD 9                     // N tiles for head gemm (132 -> 144)

typedef unsigned short ushort;
typedef short bf16x8 __attribute__((ext_vector_type(8)));
typedef float f32x4  __attribute__((ext_vector_type(4)));

__device__ inline void split2(float v, ushort& hi, ushort& lo) {
    __hip_bfloat16 h = __float2bfloat16(v);
    float r = v - __bfloat162float(h);
    __hip_bfloat16 l = __float2bfloat16(r);
    hi = *(ushort*)&h;
    lo = *(ushort*)&l;
}

__device__ inline float bf2f(ushort u) {
    union { unsigned int i; float f; } c;
    c.i = ((unsigned int)u) << 16;
    return c.f;
}

// ---------------- CSR build ----------------

__global__ void deg_k(const int* __restrict__ ei, int* __restrict__ deg) {
    int e = blockIdx.x * 256 + threadIdx.x;
    if (e >= TOT_E) return;
    int dst = (e < N_EDGES) ? ei[N_EDGES + e] : (e - N_EDGES);
    atomicAdd(&deg[dst], 1);
}

__global__ __launch_bounds__(1024) void scan_k(const int* __restrict__ deg,
                                               int* __restrict__ rowp) {
    __shared__ int part[1024];
    const int PER = 20;
    int t = threadIdx.x;
    int base = t * PER;
    int s = 0;
    for (int i = 0; i < PER; ++i) {
        int idx = base + i;
        if (idx < N_NODES) s += deg[idx];
    }
    part[t] = s;
    __syncthreads();
    for (int off = 1; off < 1024; off <<= 1) {
        int v = 0;
        if (t >= off) v = part[t - off];
        __syncthreads();
        part[t] += v;
        __syncthreads();
    }
    int run = part[t] - s;
    for (int i = 0; i < PER; ++i) {
        int idx = base + i;
        if (idx < N_NODES) { rowp[idx] = run; run += deg[idx]; }
    }
    if (t == 1023) rowp[N_NODES] = part[1023];
}

__global__ void fill_k(const int* __restrict__ ei, const int* __restrict__ rowp,
                       int* __restrict__ cur, int* __restrict__ csr) {
    int e = blockIdx.x * 256 + threadIdx.x;
    if (e >= TOT_E) return;
    int src, dst;
    if (e < N_EDGES) { src = ei[e]; dst = ei[N_EDGES + e]; }
    else             { src = dst = e - N_EDGES; }
    int p = atomicAdd(&cur[dst], 1);
    csr[rowp[dst] + p] = src;
}

// ---------------- input x -> bf16 (into hAhi, stride LDA) ----------------

__global__ void splitx_k(const float* __restrict__ x, ushort* __restrict__ ahi) {
    int idx = blockIdx.x * 256 + threadIdx.x;
    if (idx >= N_NODES * IN_CH) return;
    int n = idx >> 7, k = idx & 127;
    __hip_bfloat16 h = __float2bfloat16(x[idx]);
    ahi[(size_t)n * LDA + k] = *(ushort*)&h;
}

// ---------------- weight -> fragment-ordered hi/lo bf16 ----------------
// Wfrag[((p*NT + t)*64 + kq*16 + m)*8 + j] = W[p*32 + kq*8 + j][t*16 + m]

__global__ void convw_k(const float* __restrict__ W, int K, int NC, int NT,
                        ushort* __restrict__ fhi, ushort* __restrict__ flo,
                        int total) {
    int gid = blockIdx.x * 256 + threadIdx.x;
    if (gid >= total) return;   // total = panels*NT*64
    int p = gid / (NT * 64);
    int rem = gid % (NT * 64);
    int t = rem >> 6, c = rem & 63;
    int kq = c >> 4, m = c & 15;
    int n = t * 16 + m;
    ushort hi8[8], lo8[8];
#pragma unroll
    for (int j = 0; j < 8; ++j) {
        int k = p * 32 + kq * 8 + j;
        float v = (k < K && n < NC) ? W[(size_t)k * NC + n] : 0.f;
        split2(v, hi8[j], lo8[j]);
    }
    size_t o = ((size_t)gid) * 8;
#pragma unroll
    for (int j = 0; j < 8; ++j) { fhi[o + j] = hi8[j]; flo[o + j] = lo8[j]; }
}

// ---------------- MFMA GEMM: C[M, NC] = A[M, K] @ B[K, NC] ----------------
// A bf16 (+optional Alo for 3-term); B fragment-ordered hi/lo loaded DIRECTLY
// from global (coalesced per wave, L1-broadcast) -- no B LDS staging.

__global__ __launch_bounds__(256) void gemm_mfma(
    const ushort* __restrict__ Ahi, const ushort* __restrict__ Alo, int lda, int kpanels,
    const ushort* __restrict__ Bhi, const ushort* __restrict__ Blo, int NTtot,
    float* __restrict__ C, int ldc, int ncguard, const float* __restrict__ bias,
    ushort* __restrict__ Cb16) {
    __shared__ ushort Al[2][4][512];   // [hi/lo][wave m-tile][chunk*8]
    int tid = threadIdx.x;
    int m0 = blockIdx.x * 64;
    int t0 = blockIdx.y * 9;
    int nt = NTtot - t0; if (nt > 9) nt = 9;
    bool use3 = (Alo != nullptr);

    f32x4 acc[9];
#pragma unroll
    for (int t = 0; t < 9; ++t) acc[t] = (f32x4){0.f, 0.f, 0.f, 0.f};

    int w = tid >> 6, lane = tid & 63;

    for (int p = 0; p < kpanels; ++p) {
        int nA = use3 ? 512 : 256;
        for (int id = tid; id < nA; id += 256) {
            int hl = id >> 8;
            int cid = id & 255;
            int mrow = cid >> 2, kq = cid & 3;
            int gm = m0 + mrow;
            uint4 v = {0, 0, 0, 0};
            if (gm < N_NODES) {
                const ushort* src = (hl ? Alo : Ahi) + (size_t)gm * lda + p * 32 + kq * 8;
                v = *(const uint4*)src;
            }
            *(uint4*)&Al[hl][mrow >> 4][(kq * 16 + (mrow & 15)) * 8] = v;
        }
        __syncthreads();

        bf16x8 ahi = *(const bf16x8*)&Al[0][w][lane * 8];
        bf16x8 alo;
        if (use3) alo = *(const bf16x8*)&Al[1][w][lane * 8];
#pragma unroll
        for (int t = 0; t < 9; ++t) {
            if (t < nt) {
                size_t off = ((size_t)(p * NTtot + t0 + t) * 64 + lane) * 8;
                bf16x8 bh = *(const bf16x8*)(Bhi + off);
                bf16x8 bl = *(const bf16x8*)(Blo + off);
                acc[t] = __builtin_amdgcn_mfma_f32_16x16x32_bf16(ahi, bh, acc[t], 0, 0, 0);
                acc[t] = __builtin_amdgcn_mfma_f32_16x16x32_bf16(ahi, bl, acc[t], 0, 0, 0);
                if (use3)
                    acc[t] = __builtin_amdgcn_mfma_f32_16x16x32_bf16(alo, bh, acc[t], 0, 0, 0);
            }
        }
        __syncthreads();
    }

    // store: C/D layout col = lane&15, row = (lane>>4)*4 + r
    int rbase = m0 + w * 16 + ((lane >> 4) << 2);
    int cbase = t0 * 16 + (lane & 15);
#pragma unroll
    for (int t = 0; t < 9; ++t) {
        if (t < nt) {
            int gn = cbase + t * 16;
            if (gn >= ncguard) continue;
            float b = bias ? bias[gn] : 0.f;
#pragma unroll
            for (int r = 0; r < 4; ++r) {
                int gm = rbase + r;
                if (gm < N_NODES) {
                    float v = acc[t][r] + b;
                    C[(size_t)gm * ldc + gn] = v;
                    if (Cb16) {
                        __hip_bfloat16 bv = __float2bfloat16(v);
                        Cb16[(size_t)gm * LDB + gn] = *(ushort*)&bv;
                    }
                }
            }
        }
    }
}

// ---------------- attention logits per (node, head) ----------------

__global__ void alpha_k(const float* __restrict__ xh,
                        const float* __restrict__ a_s, const float* __restrict__ a_d,
                        float* __restrict__ as_, float* __restrict__ ad_) {
    int t = blockIdx.x * 256 + threadIdx.x;
    if (t >= N_NODES * HEADS) return;
    int n = t >> 3, h = t & 7;
    const float* row = xh + (size_t)n * LDH + h * CH;
    float ss = 0.f, sd = 0.f;
#pragma unroll
    for (int i = 0; i < CH; ++i) {
        float v = row[i];
        ss += v * a_s[h * CH + i];
        sd += v * a_d[h * CH + i];
    }
    as_[t] = ss;
    ad_[t] = sd;
}

// ---------------- fused softmax + gather-aggregate ----------------
// 4 waves/block = 4 nodes/block. Fast path (dg<=64): stats from registers.
// Feature pass: LDS-staged alpha/src, unroll-x4 independent row gathers.

__global__ __launch_bounds__(256) void gat_k(
    const ushort* __restrict__ xb, const float* __restrict__ as_,
    const float* __restrict__ ad_, const int* __restrict__ rowp,
    const int* __restrict__ csr, const float* __restrict__ bias,
    ushort* __restrict__ outhi, ushort* __restrict__ outlo) {
    int wv = threadIdx.x >> 6, lane = threadIdx.x & 63;
    int node = blockIdx.x * 4 + wv;   // grid is exactly N/4; no early return (barriers)
    int r0 = rowp[node], dg = rowp[node + 1] - r0;

    __shared__ float lex[4][64][8];
    __shared__ int   lsrc[4][64];
    __shared__ int   bdg[4];

    if (lane == 0) bdg[wv] = dg;
    __syncthreads();
    int bmax = max(max(bdg[0], bdg[1]), max(bdg[2], bdg[3]));
    int nchunks = (bmax + 63) >> 6;

    float ad[8];
#pragma unroll
    for (int h = 0; h < 8; ++h) ad[h] = ad_[node * 8 + h];

    float mx[8], iv[8], e8[8];
    int myS = node;
    bool fast = (dg <= 64);
    if (fast) {
#pragma unroll
        for (int h = 0; h < 8; ++h) e8[h] = -1e30f;
        if (lane < dg) {
            myS = csr[r0 + lane];
            const float* ap = as_ + (size_t)myS * 8;
#pragma unroll
            for (int h = 0; h < 8; ++h) {
                float e = ap[h] + ad[h];
                e8[h] = e > 0.f ? e : NEG * e;
            }
        }
#pragma unroll
        for (int h = 0; h < 8; ++h) {
            float m = e8[h];
            for (int off = 32; off; off >>= 1) m = fmaxf(m, __shfl_xor(m, off, 64));
            mx[h] = m;
        }
#pragma unroll
        for (int h = 0; h < 8; ++h) {
            float ex = (lane < dg) ? __expf(e8[h] - mx[h]) : 0.f;
            e8[h] = ex;   // now: unnormalized weight
            float s = ex;
            for (int off = 32; off; off >>= 1) s += __shfl_xor(s, off, 64);
            iv[h] = 1.0f / (s + 1e-16f);
        }
    } else {
#pragma unroll
        for (int h = 0; h < 8; ++h) mx[h] = -1e30f;
        for (int j = lane; j < dg; j += 64) {
            int s = csr[r0 + j];
            const float* ap = as_ + (size_t)s * 8;
#pragma unroll
            for (int h = 0; h < 8; ++h) {
                float e = ap[h] + ad[h];
                e = e > 0.f ? e : NEG * e;
                mx[h] = fmaxf(mx[h], e);
            }
        }
#pragma unroll
        for (int h = 0; h < 8; ++h)
            for (int off = 32; off; off >>= 1)
                mx[h] = fmaxf(mx[h], __shfl_xor(mx[h], off, 64));
        float sm[8] = {0.f, 0.f, 0.f, 0.f, 0.f, 0.f, 0.f, 0.f};
        for (int j = lane; j < dg; j += 64) {
            int s = csr[r0 + j];
            const float* ap = as_ + (size_t)s * 8;
#pragma unroll
            for (int h = 0; h < 8; ++h) {
                float e = ap[h] + ad[h];
                e = e > 0.f ? e : NEG * e;
                sm[h] += __expf(e - mx[h]);
            }
        }
#pragma unroll
        for (int h = 0; h < 8; ++h) {
            for (int off = 32; off; off >>= 1) sm[h] += __shfl_xor(sm[h], off, 64);
            iv[h] = 1.0f / (sm[h] + 1e-16f);
        }
    }

    int h0[4], h1[4];
#pragma unroll
    for (int j = 0; j < 4; ++j) {
        h0[j] = (4 * lane + j) / 33;
        h1[j] = (4 * (lane + 64) + j) / 33;   // lanes 0,1 only (always head 7)
    }
    float4 a0 = {0.f, 0.f, 0.f, 0.f}, a1 = {0.f, 0.f, 0.f, 0.f};

    for (int c = 0; c < nchunks; ++c) {
        int base = c << 6, j = base + lane;
        __syncthreads();
        // stage normalized alpha + src (pad lanes: alpha=0, src=self)
        int s = node;
        float al[8];
#pragma unroll
        for (int h = 0; h < 8; ++h) al[h] = 0.f;
        if (j < dg) {
            if (fast) {
                s = myS;
#pragma unroll
                for (int h = 0; h < 8; ++h) al[h] = e8[h] * iv[h];
            } else {
                s = csr[r0 + j];
                const float* ap = as_ + (size_t)s * 8;
#pragma unroll
                for (int h = 0; h < 8; ++h) {
                    float e = ap[h] + ad[h];
                    e = e > 0.f ? e : NEG * e;
                    al[h] = __expf(e - mx[h]) * iv[h];
                }
            }
        }
        lsrc[wv][lane] = s;
#pragma unroll
        for (int h = 0; h < 8; ++h) lex[wv][lane][h] = al[h];
        __syncthreads();

        int rem = dg - base;
        int cnt = rem > 64 ? 64 : (rem < 0 ? 0 : rem);
        int cnt4 = (cnt + 3) & ~3;
        for (int jj = 0; jj < cnt4; jj += 4) {
            int s0 = lsrc[wv][jj + 0], s1 = lsrc[wv][jj + 1];
            int s2 = lsrc[wv][jj + 2], s3 = lsrc[wv][jj + 3];
            const ushort4* p0 = (const ushort4*)(xb + (size_t)s0 * LDB);
            const ushort4* p1 = (const ushort4*)(xb + (size_t)s1 * LDB);
            const ushort4* p2 = (const ushort4*)(xb + (size_t)s2 * LDB);
            const ushort4* p3 = (const ushort4*)(xb + (size_t)s3 * LDB);
            ushort4 v0 = p0[lane], v1 = p1[lane], v2 = p2[lane], v3 = p3[lane];
            ushort4 w0, w1, w2, w3;
            if (lane < 2) { w0 = p0[64 + lane]; w1 = p1[64 + lane]; w2 = p2[64 + lane]; w3 = p3[64 + lane]; }
            const float* x0 = lex[wv][jj + 0];
            const float* x1 = lex[wv][jj + 1];
            const float* x2 = lex[wv][jj + 2];
            const float* x3 = lex[wv][jj + 3];
            a0.x += x0[h0[0]] * bf2f(v0.x) + x1[h0[0]] * bf2f(v1.x)
                  + x2[h0[0]] * bf2f(v2.x) + x3[h0[0]] * bf2f(v3.x);
            a0.y += x0[h0[1]] * bf2f(v0.y) + x1[h0[1]] * bf2f(v1.y)
                  + x2[h0[1]] * bf2f(v2.y) + x3[h0[1]] * bf2f(v3.y);
            a0.z += x0[h0[2]] * bf2f(v0.z) + x1[h0[2]] * bf2f(v1.z)
                  + x2[h0[2]] * bf2f(v2.z) + x3[h0[2]] * bf2f(v3.z);
            a0.w += x0[h0[3]] * bf2f(v0.w) + x1[h0[3]] * bf2f(v1.w)
                  + x2[h0[3]] * bf2f(v2.w) + x3[h0[3]] * bf2f(v3.w);
            if (lane < 2) {
                a1.x += x0[h1[0]] * bf2f(w0.x) + x1[h1[0]] * bf2f(w1.x)
                      + x2[h1[0]] * bf2f(w2.x) + x3[h1[0]] * bf2f(w3.x);
                a1.y += x0[h1[1]] * bf2f(w0.y) + x1[h1[1]] * bf2f(w1.y)
                      + x2[h1[1]] * bf2f(w2.y) + x3[h1[1]] * bf2f(w3.y);
                a1.z += x0[h1[2]] * bf2f(w0.z) + x1[h1[2]] * bf2f(w1.z)
                      + x2[h1[2]] * bf2f(w2.z) + x3[h1[2]] * bf2f(w3.z);
                a1.w += x0[h1[3]] * bf2f(w0.w) + x1[h1[3]] * bf2f(w1.w)
                      + x2[h1[3]] * bf2f(w2.w) + x3[h1[3]] * bf2f(w3.w);
            }
        }
    }

    // epilogue: bias + elu, bf16 (hi) out; lo only when requested (head-gemm input)
#pragma unroll
    for (int k = 0; k < 2; ++k) {
        int i4 = lane + 64 * k;
        if (i4 < 66) {
            float4 a = (k == 0) ? a0 : a1;
            float vals[4] = {a.x, a.y, a.z, a.w};
            ushort hi4[4], lo4[4];
#pragma unroll
            for (int j = 0; j < 4; ++j) {
                float v = vals[j] + bias[i4 * 4 + j];
                v = v > 0.f ? v : (__expf(v) - 1.f);
                split2(v, hi4[j], lo4[j]);
            }
            size_t o = (size_t)node * LDA + i4 * 4;
            *(ushort4*)(outhi + o) = *(ushort4*)hi4;
            if (outlo) *(ushort4*)(outlo + o) = *(ushort4*)lo4;
        } else if (i4 < 72) {
            ushort4 z = {0, 0, 0, 0};
            size_t o = (size_t)node * LDA + i4 * 4;
            *(ushort4*)(outhi + o) = z;
            if (outlo) *(ushort4*)(outlo + o) = z;
        }
    }
}

// ---------------- launch ----------------

extern "C" void kernel_launch(void* const* d_in, const int* in_sizes, int n_in,
                              void* d_out, int out_size, void* d_ws, size_t ws_size,
                              hipStream_t stream) {
    const float* x  = (const float*)d_in[0];
    const int*   ei = (const int*)d_in[1];
    const float* W[4]  = {(const float*)d_in[2],  (const float*)d_in[6],
                          (const float*)d_in[10], (const float*)d_in[14]};
    const float* As[4] = {(const float*)d_in[3],  (const float*)d_in[7],
                          (const float*)d_in[11], (const float*)d_in[15]};
    const float* Ad[4] = {(const float*)d_in[4],  (const float*)d_in[8],
                          (const float*)d_in[12], (const float*)d_in[16]};
    const float* Bb[4] = {(const float*)d_in[5],  (const float*)d_in[9],
                          (const float*)d_in[13], (const float*)d_in[17]};
    const float* Wh = (const float*)d_in[18];
    const float* bh = (const float*)d_in[19];

    // ---- workspace carve ----
    char* p = (char*)d_ws;
    float* hB    = (float*)p;           p += (size_t)N_NODES * LDH * 4;      // xh fp32
    ushort* hBb  = (ushort*)p;          p += (size_t)N_NODES * LDB * 2;      // xh bf16 payload
    ushort* hAhi = (ushort*)p;          p += (size_t)N_NODES * LDA * 2;      // A hi
    ushort* hAlo = (ushort*)p;          p += (size_t)N_NODES * LDA * 2;      // A lo (layer-3 only)
    float* as_  = (float*)p;            p += (size_t)N_NODES * HEADS * 4;
    float* ad_  = (float*)p;            p += (size_t)N_NODES * HEADS * 4;
    const int wsz0 = 4 * NT_HID * 512;
    const int wszH = 9 * NT_HID * 512;
    const int wszO = 9 * NT_HEAD * 512;
    ushort* wfhi[4]; ushort* wflo[4];
    for (int l = 0; l < 4; ++l) {
        int sz = (l == 0) ? wsz0 : wszH;
        wfhi[l] = (ushort*)p; p += (size_t)sz * 2;
        wflo[l] = (ushort*)p; p += (size_t)sz * 2;
    }
    ushort* whhi = (ushort*)p; p += (size_t)wszO * 2;
    ushort* whlo = (ushort*)p; p += (size_t)wszO * 2;
    int* deg  = (int*)p;  p += N_NODES * 4;
    int* cur  = (int*)p;  p += N_NODES * 4;
    int* rowp = (int*)p;  p += (N_NODES + 1) * 4;
    int* csr  = (int*)p;  p += (size_t)TOT_E * 4;

    // ---- CSR build ----
    hipMemsetAsync(deg, 0, sizeof(int) * 2 * N_NODES, stream);  // deg + cur
    int egrid = (TOT_E + 255) / 256;
    deg_k<<<egrid, 256, 0, stream>>>(ei, deg);
    scan_k<<<1, 1024, 0, stream>>>(deg, rowp);
    fill_k<<<egrid, 256, 0, stream>>>(ei, rowp, cur, csr);

    // ---- weight + input conversion ----
    splitx_k<<<(N_NODES * IN_CH + 255) / 256, 256, 0, stream>>>(x, hAhi);
    {
        int tot = 4 * NT_HID * 64;
        convw_k<<<(tot + 255) / 256, 256, 0, stream>>>(W[0], IN_CH, DD, NT_HID, wfhi[0], wflo[0], tot);
    }
    for (int l = 1; l < 4; ++l) {
        int tot = 9 * NT_HID * 64;
        convw_k<<<(tot + 255) / 256, 256, 0, stream>>>(W[l], DD, DD, NT_HID, wfhi[l], wflo[l], tot);
    }
    {
        int tot = 9 * NT_HEAD * 64;
        convw_k<<<(tot + 255) / 256, 256, 0, stream>>>(Wh, DD, OUTW, NT_HEAD, whhi, whlo, tot);
    }

    dim3 gG((N_NODES + 63) / 64, 2);   // hidden gemms: 17 tiles = 9 + 8
    dim3 gO((N_NODES + 63) / 64, 1);   // head gemm: 9 tiles
    int agrid = (N_NODES * HEADS + 255) / 256;
    int ggrid = N_NODES / 4;           // 5000, exact

    for (int l = 0; l < 4; ++l) {
        int kp = (l == 0) ? 4 : 9;
        gemm_mfma<<<gG, 256, 0, stream>>>(hAhi, nullptr, LDA, kp,
                                          wfhi[l], wflo[l], NT_HID,
                                          hB, LDH, LDH, nullptr, hBb);
        alpha_k<<<agrid, 256, 0, stream>>>(hB, As[l], Ad[l], as_, ad_);
        gat_k<<<ggrid, 256, 0, stream>>>(hBb, as_, ad_, rowp, csr, Bb[l],
                                         hAhi, (l == 3) ? hAlo : nullptr);
    }

    // head readout (3-term for output precision) -> fp32 out [N, 132]
    gemm_mfma<<<gO, 256, 0, stream>>>(hAhi, hAlo, LDA, 9,
                                      whhi, whlo, NT_HEAD,
                                      (float*)d_out, OUTW, OUTW, bh, nullptr);
}